// Round 14
// baseline (172.734 us; speedup 1.0000x reference)
//
#include <hip/hip_runtime.h>
#include <hip/hip_bf16.h>
#include <stdint.h>

// Problem constants (from reference)
#define NB 8
#define NT 2048
#define ND 512
#define NH 4
#define NDK 128
#define QKV_LD 1536   // row stride of qkv buffer (3*D)
#define KW 11

typedef unsigned short u16;
typedef __attribute__((ext_vector_type(4))) float f32x4;
typedef __attribute__((ext_vector_type(16))) float f32x16;
typedef __attribute__((ext_vector_type(4))) float fv4;
typedef __attribute__((ext_vector_type(8))) short s16x8;   // 8 bf16 = 4 VGPR
typedef __attribute__((ext_vector_type(4))) unsigned short u16x4;
typedef __attribute__((ext_vector_type(4))) int i32x4;

#define AS1 __attribute__((address_space(1)))
#define AS3 __attribute__((address_space(3)))

__device__ __forceinline__ u16 f2bf(float f){
  unsigned u = __float_as_uint(f);
  u += 0x7fffu + ((u >> 16) & 1u);      // RNE
  return (u16)(u >> 16);
}
__device__ __forceinline__ float bf2f(u16 h){ return __uint_as_float(((unsigned)h) << 16); }
__device__ __forceinline__ unsigned pack2bf(float a, float b){
  float2 t; t.x = a; t.y = b;
  __hip_bfloat162 h = __float22bfloat162_rn(t);
  return *reinterpret_cast<unsigned*>(&h);
}

// ---------------------------------------------------------------- fused prep:
// blocks [0,1024): x -> bf16 (grid-stride)
// blocks [1024,1792): Wqkv transpose+cvt (512x1536 -> 1536x512)
// blocks [1792,2048): Wout transpose+cvt (512x512)
__device__ __forceinline__ void transpose_body(
    const float* __restrict__ in, u16* __restrict__ out, int R, int C,
    int bx, int by, int tid)
{
  __shared__ float tile[32][33];
  const int cb = bx * 32, rb = by * 32;
  const int tx = tid & 31, ty = tid >> 5;   // (32,8)
  #pragma unroll
  for (int i = 0; i < 4; ++i)
    tile[ty + i*8][tx] = in[(size_t)(rb + ty + i*8) * C + cb + tx];
  __syncthreads();
  #pragma unroll
  for (int i = 0; i < 4; ++i)
    out[(size_t)(cb + ty + i*8) * R + rb + tx] = f2bf(tile[tx][ty + i*8]);
}

__global__ void prep_kernel(const float* __restrict__ x, u16* __restrict__ xb,
                            const float* __restrict__ Wqkv, u16* __restrict__ wqkvT,
                            const float* __restrict__ Wout, u16* __restrict__ woutT)
{
  const int bid = blockIdx.x, tid = threadIdx.x;
  if (bid < 1024){
    const int n4 = (NB*NT*ND)/4;
    for (int i = bid*256 + tid; i < n4; i += 1024*256){
      float4 v = reinterpret_cast<const float4*>(x)[i];
      u16x4 o = { f2bf(v.x), f2bf(v.y), f2bf(v.z), f2bf(v.w) };
      reinterpret_cast<u16x4*>(xb)[i] = o;
    }
  } else if (bid < 1792){
    const int idx = bid - 1024;              // grid (48,16)
    transpose_body(Wqkv, wqkvT, 512, 1536, idx % 48, idx / 48, tid);
  } else {
    const int idx = bid - 1792;              // grid (16,16)
    transpose_body(Wout, woutT, 512, 512, idx % 16, idx / 16, tid);
  }
}

// ---------------------------------------------------------------- bf16 GEMM  C = A * Bt^T + bias
// BK=64 + XOR swizzle (rule #21, verified R13): linear global_load_lds dest, source
// col-chunk pre-swizzled c^(row&7); frag reads at (kk*4+g)^(r15&7).
// EPI==0: C -> bf16; v-range blocks (n0 >= 2*ND) also write transposed V (vT).
// EPI==1: C -> f32 out with FUSED FSMN epilogue.
template<int EPI>
__global__ __launch_bounds__(256, 2) void gemm_bt(
    const u16* __restrict__ A, const u16* __restrict__ Bt, const float* __restrict__ bias,
    u16* __restrict__ Cb, float* __restrict__ Cf, u16* __restrict__ vTout,
    const u16* __restrict__ qkvb, const float* __restrict__ mask,
    const float* __restrict__ fsmn_w,
    int M, int N, int Kd)
{
  __shared__ u16 As[128 * 64];
  __shared__ u16 Bs[128 * 64];
  const int tid = threadIdx.x;
  const int m0 = blockIdx.y * 128, n0 = blockIdx.x * 128;
  const int w = tid >> 6, l = tid & 63, wr = w >> 1, wc = w & 1;
  const int r15 = l & 15, g = l >> 4;

  f32x4 acc[4][4] = {};

  const int r0 = tid >> 3;
  const int scol8 = ((tid & 7) ^ (r0 & 7)) << 3;   // u16 offset within the 64-col row
  const u16* Ag = A  + (size_t)(m0 + r0) * Kd + scol8;
  const u16* Bg = Bt + (size_t)(n0 + r0) * Kd + scol8;
  u16* Al = &As[(size_t)tid * 8];
  u16* Bl = &Bs[(size_t)tid * 8];

  for (int k0 = 0; k0 < Kd; k0 += 64){
    #pragma unroll
    for (int i = 0; i < 4; ++i)
      __builtin_amdgcn_global_load_lds((AS1 void*)(Ag + (size_t)(i*32) * Kd + k0),
                                       (AS3 void*)(Al + i*2048), 16, 0, 0);
    #pragma unroll
    for (int i = 0; i < 4; ++i)
      __builtin_amdgcn_global_load_lds((AS1 void*)(Bg + (size_t)(i*32) * Kd + k0),
                                       (AS3 void*)(Bl + i*2048), 16, 0, 0);
    __syncthreads();
    #pragma unroll
    for (int kk = 0; kk < 2; ++kk){
      s16x8 af[4], bfr[4];
      #pragma unroll
      for (int m = 0; m < 4; ++m){
        const int R = wr*64 + m*16 + r15;
        af[m] = *reinterpret_cast<const s16x8*>(
            &As[R*64 + (((kk*4 + g) ^ (r15 & 7)) << 3)]);
      }
      #pragma unroll
      for (int n = 0; n < 4; ++n){
        const int R = wc*64 + n*16 + r15;
        bfr[n] = *reinterpret_cast<const s16x8*>(
            &Bs[R*64 + (((kk*4 + g) ^ (r15 & 7)) << 3)]);
      }
      #pragma unroll
      for (int m = 0; m < 4; ++m){
        #pragma unroll
        for (int n = 0; n < 4; ++n)
          acc[m][n] = __builtin_amdgcn_mfma_f32_16x16x32_bf16(af[m], bfr[n], acc[m][n], 0, 0, 0);
      }
    }
    __syncthreads();
  }

  if (EPI == 0){
    const bool vrange = (n0 >= 2*ND);            // block-uniform (128-aligned ranges)
    #pragma unroll
    for (int m = 0; m < 4; ++m){
      const int gr0 = m0 + wr*64 + m*16 + g*4;
      #pragma unroll
      for (int n = 0; n < 4; ++n){
        const int gc = n0 + wc*64 + n*16 + r15;
        const float bv = bias[gc];
        u16x4 pk;
        #pragma unroll
        for (int j = 0; j < 4; ++j){
          const u16 hv = f2bf(acc[m][n][j] + bv);
          Cb[(size_t)(gr0 + j) * N + gc] = hv;
          pk[j] = hv;
        }
        if (vrange){                              // also write transposed V
          const int d  = gc - 2*ND;
          const int bh = (gr0 >> 11) * NH + (d >> 7);
          const int dk = d & 127, t = gr0 & 2047;
          *reinterpret_cast<u16x4*>(&vTout[((size_t)bh * NDK + dk) * NT + t]) = pk;
        }
      }
    }
  } else {
    // fused FSMN epilogue
    float wv[4][KW];
    #pragma unroll
    for (int n = 0; n < 4; ++n){
      const int gc = n0 + wc*64 + n*16 + r15;
      #pragma unroll
      for (int i = 0; i < KW; ++i) wv[n][i] = fsmn_w[gc*KW + i];
    }
    #pragma unroll
    for (int m = 0; m < 4; ++m){
      const int gr0 = m0 + wr*64 + m*16 + g*4;
      const int bb = gr0 >> 11, t0 = gr0 & 2047;
      const float* mb = mask + (size_t)bb * NT;
      float mk[14];
      #pragma unroll
      for (int i = 0; i < 14; ++i){
        const int tau = t0 - 5 + i;
        mk[i] = ((unsigned)tau < (unsigned)NT) ? mb[tau] : 0.f;
      }
      #pragma unroll
      for (int n = 0; n < 4; ++n){
        const int gc = n0 + wc*64 + n*16 + r15;
        const float bv = bias[gc];
        const u16* vb = qkvb + (size_t)bb * NT * QKV_LD + 2*ND + gc;
        float vmv[14];
        #pragma unroll
        for (int i = 0; i < 14; ++i){
          const ptrdiff_t tau = t0 - 5 + i;
          vmv[i] = mk[i] * bf2f(vb[tau * QKV_LD]);   // mk=0 zeroes OOB taps
        }
        #pragma unroll
        for (int j = 0; j < 4; ++j){
          float conv = vmv[5 + j];                    // vm[t] residual term
          #pragma unroll
          for (int i = 0; i < KW; ++i) conv = fmaf(wv[n][i], vmv[j + i], conv);
          Cf[(size_t)(gr0 + j) * N + gc] = acc[m][n][j] + bv + mk[5 + j] * conv;
        }
      }
    }
  }
}

// ---------------------------------------------------------------- flash attention, KV-SPLIT x2
// Grid 1024 = 32 bh x 16 qblk x 2 KV-halves. LDS 32KB (K and V single-buffered) ->
// 4 blocks/CU = 4 waves/SIMD (2x the latency hiding of R10's 2-block config).
// 2 barriers/tile: A (after QK; frees Ks -> stage K(t+1)), B (after PV; frees Vs ->
// stage V(t+1)). Each barrier's implicit vmcnt(0) drains the opposite stage with
// >=600 cyc of compute as latency cover (K/V mostly L2-resident).
// Blocks emit UNNORMALIZED bf16 O-partials + (m,l) f32; combine_kernel merges halves.
// Swapped QK^T: mfma(A=K, B=Q) -> lane owns ONE q-row, 32 scores in D regs.
// P->A-frag via 2x v_permlane32_swap_b32 per k-step.
// VGPR must stay <= 128 (4 waves/SIMD cliff, m69). DO NOT raise launch_bounds arg (R9).
#define ATT_MFMA(a, bb, c) __builtin_amdgcn_mfma_f32_32x32x16_bf16(a, bb, c, 0, 0, 0)
#define C1F 0.12751741567f   /* (1/sqrt(128)) * log2(e) */

__global__ __launch_bounds__(256, 2) void attn_kernel(
    const u16* __restrict__ qkvb, const u16* __restrict__ vT,
    const float* __restrict__ mask, u16* __restrict__ op0,
    u16* __restrict__ op1, float* __restrict__ mlpart)
{
  __shared__ u16 Ks[64 * 128];   // [key][dk], swizzled 16B chunks (single buffer)
  __shared__ u16 Vs[128 * 64];   // [dk][key], swizzled 16B chunks (single buffer)
  const int tid = threadIdx.x;
  const int w = tid >> 6, l = tid & 63, l31 = l & 31, hi = l >> 5;

  // XCD-bijective remap: all 32 blocks of one bh land on one XCD (K/V L2 locality)
  const int lin = blockIdx.x + blockIdx.y * 8;    // grid = (8, 128)
  const int xcd = lin & 7, jj = lin >> 3;         // jj 0..127
  const int bh = xcd * 4 + (jj & 3);
  const int half = (jj >> 2) & 1, qblk = jj >> 3;
  const int b = bh >> 2, h = bh & 3;
  const int q0 = qblk * 128;
  const int kvlo = half * (NT/2);

  const u16* qptr = qkvb + (size_t)b * NT * QKV_LD + h * NDK;
  const u16* kb   = qptr + ND;
  const u16* vtb  = vT + (size_t)bh * NDK * NT;
  const float* mkp = mask + (size_t)b * NT;

  // Q in registers (B-operand): lane holds Q[q0+w*32+l31][s*16 + hi*8 .. +7]
  s16x8 qf[8];
  {
    const u16* qrow = qptr + (size_t)(q0 + w*32 + l31) * QKV_LD;
    #pragma unroll
    for (int s = 0; s < 8; ++s)
      qf[s] = *reinterpret_cast<const s16x8*>(qrow + s*16 + hi*8);
  }

  float mrun = -1e30f, lrun = 0.f;
  f32x16 o0 = {}, o1 = {}, o2 = {}, o3 = {};

  // K chunk c: key = c>>4, slot = c&15 (256B contiguous per key row, source XOR-swizzled).
  // V chunk c: dk = c>>3, kslot = c&7 (128B contiguous per dk row).
#define STAGE_K(kvo) do { \
    _Pragma("unroll") \
    for (int i_ = 0; i_ < 4; ++i_){ \
      const int n_ = i_*256 + tid, kr_ = n_ >> 4, c_ = n_ & 15; \
      const u16* gp_ = kb + (size_t)((kvo) + kr_) * QKV_LD + ((c_ ^ (kr_ & 7)) << 3); \
      __builtin_amdgcn_global_load_lds((AS1 void*)gp_, (AS3 void*)&Ks[n_*8], 16, 0, 0); \
    } \
  } while(0)
#define STAGE_V(kvo) do { \
    _Pragma("unroll") \
    for (int i_ = 0; i_ < 4; ++i_){ \
      const int n_ = i_*256 + tid, dr_ = n_ >> 3, kc_ = n_ & 7; \
      const u16* gp_ = vtb + (size_t)dr_ * NT + (kvo) + ((kc_ ^ (dr_ & 7)) << 3); \
      __builtin_amdgcn_global_load_lds((AS1 void*)gp_, (AS3 void*)&Vs[n_*8], 16, 0, 0); \
    } \
  } while(0)

  STAGE_K(kvlo);
  STAGE_V(kvlo);
  __syncthreads();

  for (int t = 0; t < 16; ++t){
    const int kv0 = kvlo + t * 64;

    // mask for this tile: lane's k-locals are b32*32 + r8*8 + 4*hi + j
    fv4 mA[4], mB[4];
    #pragma unroll
    for (int r8 = 0; r8 < 4; ++r8){
      mA[r8] = *reinterpret_cast<const fv4*>(&mkp[kv0      + r8*8 + hi*4]);
      mB[r8] = *reinterpret_cast<const fv4*>(&mkp[kv0 + 32 + r8*8 + hi*4]);
    }

    // S^T = K Q^T: d0 keys kv0+0..31, d1 keys kv0+32..63; lane owns q-col l31
    f32x16 d0 = {}, d1 = {};
    __builtin_amdgcn_s_setprio(1);
    #pragma unroll
    for (int s = 0; s < 8; ++s){
      const int cg = s*2 + hi;
      s16x8 kf0 = *reinterpret_cast<const s16x8*>(
          &Ks[ l31*128      + ((cg ^ (l31 & 7)) << 3) ]);
      s16x8 kf1 = *reinterpret_cast<const s16x8*>(
          &Ks[ (32+l31)*128 + ((cg ^ (l31 & 7)) << 3) ]);
      d0 = ATT_MFMA(kf0, qf[s], d0);
      d1 = ATT_MFMA(kf1, qf[s], d1);
    }
    __builtin_amdgcn_s_setprio(0);

    __syncthreads();                 // A: all waves done reading Ks; drains V-stage
    if (t + 1 < 16) STAGE_K(kv0 + 64);

    // row max over raw scores: max3-friendly tree, then cross-half
    float mx0 = fmaxf(d0[0], d0[1]), mx1 = fmaxf(d0[2], d0[3]);
    float mx2 = fmaxf(d1[0], d1[1]), mx3 = fmaxf(d1[2], d1[3]);
    #pragma unroll
    for (int r = 4; r < 16; r += 4){
      mx0 = fmaxf(mx0, fmaxf(d0[r],   d0[r+1]));
      mx1 = fmaxf(mx1, fmaxf(d0[r+2], d0[r+3]));
      mx2 = fmaxf(mx2, fmaxf(d1[r],   d1[r+1]));
      mx3 = fmaxf(mx3, fmaxf(d1[r+2], d1[r+3]));
    }
    float tmx = fmaxf(fmaxf(mx0, mx1), fmaxf(mx2, mx3));
    tmx = fmaxf(tmx, __shfl_xor(tmx, 32));

    // T13 defer-max (raw-score threshold 64 ~ 8 nats)
    if (!__all(tmx <= mrun + 64.f)){
      const float mn = fmaxf(mrun, tmx);
      const float corr = __builtin_amdgcn_exp2f((mrun - mn) * C1F);
      mrun = mn; lrun *= corr;
      #pragma unroll
      for (int r = 0; r < 16; ++r){
        const int qs = (r & 3) + 8*(r >> 2) + 4*hi;
        const float cq = __shfl(corr, qs);
        o0[r] *= cq; o1[r] *= cq; o2[r] *= cq; o3[r] *= cq;
      }
    }

    // p = exp2(fma(s, c1, -m*c1)) * mask; in-place into d0/d1; accumulate l
    const float mm = mrun * C1F;
    float ts = 0.f;
    #pragma unroll
    for (int r = 0; r < 16; ++r){
      const int r8 = r >> 2, j = r & 3;
      const float p0 = __builtin_amdgcn_exp2f(fmaf(d0[r], C1F, -mm)) * mA[r8][j];
      const float p1 = __builtin_amdgcn_exp2f(fmaf(d1[r], C1F, -mm)) * mB[r8][j];
      d0[r] = p0; d1[r] = p1; ts += p0 + p1;
    }
    ts += __shfl_xor(ts, 32);
    lrun += ts;

    // pack p -> bf16 pairs
    unsigned pku[2][4][2];
    #pragma unroll
    for (int r8 = 0; r8 < 4; ++r8){
      pku[0][r8][0] = pack2bf(d0[4*r8+0], d0[4*r8+1]);
      pku[0][r8][1] = pack2bf(d0[4*r8+2], d0[4*r8+3]);
      pku[1][r8][0] = pack2bf(d1[4*r8+0], d1[4*r8+1]);
      pku[1][r8][1] = pack2bf(d1[4*r8+2], d1[4*r8+3]);
    }

    // PV: per k-step build A-frag with 2 permlane32_swap, then 4 dk-blocks
    #pragma unroll
    for (int ks = 0; ks < 4; ++ks){
      const int bb = ks >> 1, rlo = (ks & 1) * 2;
      int u0 = (int)pku[bb][rlo][0],   u1 = (int)pku[bb][rlo][1];
      int v0 = (int)pku[bb][rlo+1][0], v1 = (int)pku[bb][rlo+1][1];
      asm("v_permlane32_swap_b32 %0, %1" : "+v"(u0), "+v"(v0));
      asm("v_permlane32_swap_b32 %0, %1" : "+v"(u1), "+v"(v1));
      union { i32x4 i; s16x8 hv; } pu;
      pu.i[0] = u0; pu.i[1] = u1; pu.i[2] = v0; pu.i[3] = v1;
      const int cg = ks*2 + hi;
      s16x8 vf0 = *reinterpret_cast<const s16x8*>(&Vs[ (l31     )*64 + ((cg ^ (l31 & 7)) << 3) ]);
      s16x8 vf1 = *reinterpret_cast<const s16x8*>(&Vs[ (32 + l31)*64 + ((cg ^ (l31 & 7)) << 3) ]);
      s16x8 vf2 = *reinterpret_cast<const s16x8*>(&Vs[ (64 + l31)*64 + ((cg ^ (l31 & 7)) << 3) ]);
      s16x8 vf3 = *reinterpret_cast<const s16x8*>(&Vs[ (96 + l31)*64 + ((cg ^ (l31 & 7)) << 3) ]);
      __builtin_amdgcn_s_setprio(1);
      o0 = ATT_MFMA(pu.hv, vf0, o0);
      o1 = ATT_MFMA(pu.hv, vf1, o1);
      o2 = ATT_MFMA(pu.hv, vf2, o2);
      o3 = ATT_MFMA(pu.hv, vf3, o3);
      __builtin_amdgcn_s_setprio(0);
    }

    __syncthreads();                 // B: all waves done reading Vs; drains K-stage
    if (t + 1 < 16) STAGE_V(kv0 + 64);
  }

  // epilogue: UNNORMALIZED partial O -> op[half]; (m,l) -> mlpart
  u16* opb = (half == 0) ? op0 : op1;
  #pragma unroll
  for (int r = 0; r < 16; ++r){
    const int qs = (r & 3) + 8*(r >> 2) + 4*hi;
    const int row = q0 + w*32 + qs;
    u16* cp = opb + (size_t)(b*NT + row) * ND + h*NDK + l31;
    cp[0]  = f2bf(o0[r]);
    cp[32] = f2bf(o1[r]);
    cp[64] = f2bf(o2[r]);
    cp[96] = f2bf(o3[r]);
  }
  if (hi == 0){
    const int row = q0 + w*32 + l31;
    float2 v; v.x = mrun; v.y = lrun;
    reinterpret_cast<float2*>(mlpart)[ ((size_t)half*32 + bh)*NT + row ] = v;
  }
#undef STAGE_K
#undef STAGE_V
}

// ---------------------------------------------------------------- combine KV-split halves
// ctx = (o0*e0 + o1*e1) / (l0*e0 + l1*e1), e_i = exp2((m_i - max(m))*C1F).
// In-place safe: each thread reads then writes only its own 4 elements of p0(==ctxb).
__global__ void combine_kernel(const u16* __restrict__ p0, const u16* __restrict__ p1,
                               const float* __restrict__ mlpart, u16* __restrict__ ctxb)
{
  const int idx = blockIdx.x * 256 + threadIdx.x;   // NB*NT*ND/4 threads
  const int rg = idx >> 7;            // b*NT + row
  const int cc = (idx & 127) << 2;    // col 0..508
  const int bh = ((rg >> 11) << 2) + (cc >> 7);
  const int row = rg & 2047;
  const float2 ml0 = reinterpret_cast<const float2*>(mlpart)[ (size_t)bh*NT + row ];
  const float2 ml1 = reinterpret_cast<const float2*>(mlpart)[ (size_t)(32 + bh)*NT + row ];
  const float ms = fmaxf(ml0.x, ml1.x);
  const float e0 = __builtin_amdgcn_exp2f((ml0.x - ms) * C1F);
  const float e1 = __builtin_amdgcn_exp2f((ml1.x - ms) * C1F);
  const float den = ml0.y * e0 + ml1.y * e1;
  const float s0 = (den > 0.f) ? e0 / den : 0.f;
  const float s1 = (den > 0.f) ? e1 / den : 0.f;
  const u16x4 a0 = *reinterpret_cast<const u16x4*>(&p0[(size_t)idx * 4]);
  const u16x4 a1 = *reinterpret_cast<const u16x4*>(&p1[(size_t)idx * 4]);
  u16x4 o;
  #pragma unroll
  for (int j = 0; j < 4; ++j)
    o[j] = f2bf(bf2f(a0[j]) * s0 + bf2f(a1[j]) * s1);
  *reinterpret_cast<u16x4*>(&ctxb[(size_t)idx * 4]) = o;
}

// ---------------------------------------------------------------- launcher
extern "C" void kernel_launch(void* const* d_in, const int* in_sizes, int n_in,
                              void* d_out, int out_size, void* d_ws, size_t ws_size,
                              hipStream_t stream) {
  const float* x      = (const float*)d_in[0];
  const float* mask   = (const float*)d_in[1];
  const float* Wqkv   = (const float*)d_in[2];
  const float* bqkv   = (const float*)d_in[3];
  const float* Wout   = (const float*)d_in[4];
  const float* bout   = (const float*)d_in[5];
  const float* fsmn_w = (const float*)d_in[6];
  float* out = (float*)d_out;

  // workspace layout (bytes), total ~103 MB (same extent as R10/R13):
  // xb dead after gemm<0> -> reused as O-partial half-1; ctxb holds O-partial half-0
  // then the combined ctx (in-place); wqkvT dead after gemm<0> -> reused as mlpart (1MB).
  char* ws = (char*)d_ws;
  u16* xb    = (u16*)ws;                         // 16,777,216
  u16* wqkvT = (u16*)(ws + 16777216);            //  1,572,864
  u16* woutT = (u16*)(ws + 18350080);            //    524,288
  u16* qkvb  = (u16*)(ws + 18874368);            // 50,331,648
  u16* ctxb  = (u16*)(ws + 69206016);            // 16,777,216
  u16* vT    = (u16*)(ws + 85983232);            // 16,777,216  (total 102,760,448)

  prep_kernel<<<2048, 256, 0, stream>>>(x, xb, Wqkv, wqkvT, Wout, woutT);
  gemm_bt<0><<<dim3(1536/128, 16384/128), 256, 0, stream>>>(
      xb, wqkvT, bqkv, qkvb, nullptr, vT, nullptr, nullptr, nullptr, NB*NT, QKV_LD, ND);
  attn_kernel<<<dim3(8, 128), 256, 0, stream>>>(
      qkvb, vT, mask, ctxb, xb, (float*)wqkvT);
  combine_kernel<<<(NB*NT*ND/4)/256, 256, 0, stream>>>(
      ctxb, xb, (const float*)wqkvT, ctxb);
  gemm_bt<1><<<dim3(512/128, 16384/128), 256, 0, stream>>>(
      ctxb, woutT, bout, nullptr, out, nullptr, qkvb, mask, fsmn_w, NB*NT, ND, ND);
}

// Round 15
// 161.797 us; speedup vs baseline: 1.0676x; 1.0676x over previous
//
#include <hip/hip_runtime.h>
#include <hip/hip_bf16.h>
#include <stdint.h>

// Problem constants (from reference)
#define NB 8
#define NT 2048
#define ND 512
#define NH 4
#define NDK 128
#define QKV_LD 1536   // row stride of qkv buffer (3*D)
#define KW 11

typedef unsigned short u16;
typedef __attribute__((ext_vector_type(4))) float f32x4;
typedef __attribute__((ext_vector_type(16))) float f32x16;
typedef __attribute__((ext_vector_type(4))) float fv4;
typedef __attribute__((ext_vector_type(8))) short s16x8;   // 8 bf16 = 4 VGPR
typedef __attribute__((ext_vector_type(4))) unsigned short u16x4;
typedef __attribute__((ext_vector_type(4))) int i32x4;

#define AS1 __attribute__((address_space(1)))
#define AS3 __attribute__((address_space(3)))

__device__ __forceinline__ u16 f2bf(float f){
  unsigned u = __float_as_uint(f);
  u += 0x7fffu + ((u >> 16) & 1u);      // RNE
  return (u16)(u >> 16);
}
__device__ __forceinline__ float bf2f(u16 h){ return __uint_as_float(((unsigned)h) << 16); }
__device__ __forceinline__ unsigned pack2bf(float a, float b){
  float2 t; t.x = a; t.y = b;
  __hip_bfloat162 h = __float22bfloat162_rn(t);
  return *reinterpret_cast<unsigned*>(&h);
}

// ---------------------------------------------------------------- fused prep:
// blocks [0,1024): x -> bf16 (grid-stride)
// blocks [1024,1792): Wqkv transpose+cvt (512x1536 -> 1536x512)
// blocks [1792,2048): Wout transpose+cvt (512x512)
__device__ __forceinline__ void transpose_body(
    const float* __restrict__ in, u16* __restrict__ out, int R, int C,
    int bx, int by, int tid)
{
  __shared__ float tile[32][33];
  const int cb = bx * 32, rb = by * 32;
  const int tx = tid & 31, ty = tid >> 5;   // (32,8)
  #pragma unroll
  for (int i = 0; i < 4; ++i)
    tile[ty + i*8][tx] = in[(size_t)(rb + ty + i*8) * C + cb + tx];
  __syncthreads();
  #pragma unroll
  for (int i = 0; i < 4; ++i)
    out[(size_t)(cb + ty + i*8) * R + rb + tx] = f2bf(tile[tx][ty + i*8]);
}

__global__ void prep_kernel(const float* __restrict__ x, u16* __restrict__ xb,
                            const float* __restrict__ Wqkv, u16* __restrict__ wqkvT,
                            const float* __restrict__ Wout, u16* __restrict__ woutT)
{
  const int bid = blockIdx.x, tid = threadIdx.x;
  if (bid < 1024){
    const int n4 = (NB*NT*ND)/4;
    for (int i = bid*256 + tid; i < n4; i += 1024*256){
      float4 v = reinterpret_cast<const float4*>(x)[i];
      u16x4 o = { f2bf(v.x), f2bf(v.y), f2bf(v.z), f2bf(v.w) };
      reinterpret_cast<u16x4*>(xb)[i] = o;
    }
  } else if (bid < 1792){
    const int idx = bid - 1024;              // grid (48,16)
    transpose_body(Wqkv, wqkvT, 512, 1536, idx % 48, idx / 48, tid);
  } else {
    const int idx = bid - 1792;              // grid (16,16)
    transpose_body(Wout, woutT, 512, 512, idx % 16, idx / 16, tid);
  }
}

// ---------------------------------------------------------------- bf16 GEMM  C = A * Bt^T + bias
// BK=64 + XOR swizzle (rule #21, verified R13): linear global_load_lds dest, source
// col-chunk pre-swizzled c^(row&7); frag reads at (kk*4+g)^(r15&7).
// EPI==0: C -> bf16; v-range blocks (n0 >= 2*ND) also write V in the SUBTILED-vT layout:
//   per (bh, 64-key tile): [cg = key/8][dk][8 keys] of 16B chunks (8192 u16/tile) ->
//   attn stages it as a pure linear copy and reads it conflict-free (R15).
// EPI==1: C -> f32 out with FUSED FSMN epilogue.
template<int EPI>
__global__ __launch_bounds__(256, 2) void gemm_bt(
    const u16* __restrict__ A, const u16* __restrict__ Bt, const float* __restrict__ bias,
    u16* __restrict__ Cb, float* __restrict__ Cf, u16* __restrict__ vTout,
    const u16* __restrict__ qkvb, const float* __restrict__ mask,
    const float* __restrict__ fsmn_w,
    int M, int N, int Kd)
{
  __shared__ u16 As[128 * 64];
  __shared__ u16 Bs[128 * 64];
  const int tid = threadIdx.x;
  const int m0 = blockIdx.y * 128, n0 = blockIdx.x * 128;
  const int w = tid >> 6, l = tid & 63, wr = w >> 1, wc = w & 1;
  const int r15 = l & 15, g = l >> 4;

  f32x4 acc[4][4] = {};

  const int r0 = tid >> 3;
  const int scol8 = ((tid & 7) ^ (r0 & 7)) << 3;   // u16 offset within the 64-col row
  const u16* Ag = A  + (size_t)(m0 + r0) * Kd + scol8;
  const u16* Bg = Bt + (size_t)(n0 + r0) * Kd + scol8;
  u16* Al = &As[(size_t)tid * 8];
  u16* Bl = &Bs[(size_t)tid * 8];

  for (int k0 = 0; k0 < Kd; k0 += 64){
    #pragma unroll
    for (int i = 0; i < 4; ++i)
      __builtin_amdgcn_global_load_lds((AS1 void*)(Ag + (size_t)(i*32) * Kd + k0),
                                       (AS3 void*)(Al + i*2048), 16, 0, 0);
    #pragma unroll
    for (int i = 0; i < 4; ++i)
      __builtin_amdgcn_global_load_lds((AS1 void*)(Bg + (size_t)(i*32) * Kd + k0),
                                       (AS3 void*)(Bl + i*2048), 16, 0, 0);
    __syncthreads();
    #pragma unroll
    for (int kk = 0; kk < 2; ++kk){
      s16x8 af[4], bfr[4];
      #pragma unroll
      for (int m = 0; m < 4; ++m){
        const int R = wr*64 + m*16 + r15;
        af[m] = *reinterpret_cast<const s16x8*>(
            &As[R*64 + (((kk*4 + g) ^ (r15 & 7)) << 3)]);
      }
      #pragma unroll
      for (int n = 0; n < 4; ++n){
        const int R = wc*64 + n*16 + r15;
        bfr[n] = *reinterpret_cast<const s16x8*>(
            &Bs[R*64 + (((kk*4 + g) ^ (r15 & 7)) << 3)]);
      }
      #pragma unroll
      for (int m = 0; m < 4; ++m){
        #pragma unroll
        for (int n = 0; n < 4; ++n)
          acc[m][n] = __builtin_amdgcn_mfma_f32_16x16x32_bf16(af[m], bfr[n], acc[m][n], 0, 0, 0);
      }
    }
    __syncthreads();
  }

  if (EPI == 0){
    const bool vrange = (n0 >= 2*ND);            // block-uniform (128-aligned ranges)
    #pragma unroll
    for (int m = 0; m < 4; ++m){
      const int gr0 = m0 + wr*64 + m*16 + g*4;
      #pragma unroll
      for (int n = 0; n < 4; ++n){
        const int gc = n0 + wc*64 + n*16 + r15;
        const float bv = bias[gc];
        u16x4 pk;
        #pragma unroll
        for (int j = 0; j < 4; ++j){
          const u16 hv = f2bf(acc[m][n][j] + bv);
          Cb[(size_t)(gr0 + j) * N + gc] = hv;
          pk[j] = hv;
        }
        if (vrange){                              // write V in subtiled-vT layout
          const int d  = gc - 2*ND;
          const int bh = (gr0 >> 11) * NH + (d >> 7);
          const int dk = d & 127, t = gr0 & 2047;   // t%8 in {0,4}: pk fits one chunk
          u16* dst = vTout + (size_t)bh * (NDK*NT)
                   + (t >> 6) * 8192 + ((t & 63) >> 3) * 1024 + dk * 8 + (t & 7);
          *reinterpret_cast<u16x4*>(dst) = pk;
        }
      }
    }
  } else {
    // fused FSMN epilogue
    float wv[4][KW];
    #pragma unroll
    for (int n = 0; n < 4; ++n){
      const int gc = n0 + wc*64 + n*16 + r15;
      #pragma unroll
      for (int i = 0; i < KW; ++i) wv[n][i] = fsmn_w[gc*KW + i];
    }
    #pragma unroll
    for (int m = 0; m < 4; ++m){
      const int gr0 = m0 + wr*64 + m*16 + g*4;
      const int bb = gr0 >> 11, t0 = gr0 & 2047;
      const float* mb = mask + (size_t)bb * NT;
      float mk[14];
      #pragma unroll
      for (int i = 0; i < 14; ++i){
        const int tau = t0 - 5 + i;
        mk[i] = ((unsigned)tau < (unsigned)NT) ? mb[tau] : 0.f;
      }
      #pragma unroll
      for (int n = 0; n < 4; ++n){
        const int gc = n0 + wc*64 + n*16 + r15;
        const float bv = bias[gc];
        const u16* vb = qkvb + (size_t)bb * NT * QKV_LD + 2*ND + gc;
        float vmv[14];
        #pragma unroll
        for (int i = 0; i < 14; ++i){
          const ptrdiff_t tau = t0 - 5 + i;
          vmv[i] = mk[i] * bf2f(vb[tau * QKV_LD]);   // mk=0 zeroes OOB taps
        }
        #pragma unroll
        for (int j = 0; j < 4; ++j){
          float conv = vmv[5 + j];                    // vm[t] residual term
          #pragma unroll
          for (int i = 0; i < KW; ++i) conv = fmaf(wv[n][i], vmv[j + i], conv);
          Cf[(size_t)(gr0 + j) * N + gc] = acc[m][n][j] + bv + mk[5 + j] * conv;
        }
      }
    }
  }
}

// ---------------------------------------------------------------- flash attention (4-wave, 32x32x16)
// R13/R10 structure (verified 110us) + subtiled-vT (R15): V staging is a LINEAR copy
// (contiguous source) and PV ds_read_b128 is conflict-free ([cg][dk][16B] chunks).
// 256 thr = 4 waves x 32 q-rows; grid 512 = 2 independent blocks/CU (m114 overlap).
// Swapped QK^T: mfma(A=K, B=Q) -> lane owns ONE q-row, 32 scores in D regs.
// P->A-frag via 2x v_permlane32_swap_b32 per k-step. Single score set.
// DO NOT raise launch_bounds 2nd arg (R9: (256,3) -> 84 VGPR + scratch spill, 2.2x slower).
#define ATT_MFMA(a, bb, c) __builtin_amdgcn_mfma_f32_32x32x16_bf16(a, bb, c, 0, 0, 0)
#define C1F 0.12751741567f   /* (1/sqrt(128)) * log2(e) */

__global__ __launch_bounds__(256, 2) void attn_kernel(
    const u16* __restrict__ qkvb, const u16* __restrict__ vT,
    const float* __restrict__ mask, u16* __restrict__ ctxb)
{
  __shared__ u16 Ks[2][64 * 128];   // [key][dk], swizzled 16B chunks
  __shared__ u16 Vs[2][8 * 128 * 8];// [cg][dk][8 keys] subtiled (linear image of vT tile)
  const int tid = threadIdx.x;
  const int w = tid >> 6, l = tid & 63, l31 = l & 31, hi = l >> 5;

  // XCD-bijective remap: all 16 q-blocks of one bh land on one XCD (K/V L2 locality)
  const int lin = blockIdx.x + blockIdx.y * 8;    // grid = (8, 64)
  const int xcd = lin & 7, jj = lin >> 3;         // jj 0..63
  const int bh = xcd * 4 + (jj & 3), qblk = jj >> 2;
  const int b = bh >> 2, h = bh & 3;
  const int q0 = qblk * 128;

  const u16* qptr = qkvb + (size_t)b * NT * QKV_LD + h * NDK;
  const u16* kb   = qptr + ND;
  const u16* vtb  = vT + (size_t)bh * (NDK*NT);
  const float* mkp = mask + (size_t)b * NT;

  // Q in registers (B-operand): lane holds Q[q0+w*32+l31][s*16 + hi*8 .. +7]
  s16x8 qf[8];
  {
    const u16* qrow = qptr + (size_t)(q0 + w*32 + l31) * QKV_LD;
    #pragma unroll
    for (int s = 0; s < 8; ++s)
      qf[s] = *reinterpret_cast<const s16x8*>(qrow + s*16 + hi*8);
  }

  float mrun = -1e30f, lrun = 0.f;
  f32x16 o0 = {}, o1 = {}, o2 = {}, o3 = {};

  // K chunk c: key = c>>4, slot = c&15 (256B contiguous per key row, source XOR-swizzled).
  // V: contiguous linear copy of the 16KB subtiled-vT tile (kvo/64).
#define STAGE(buf, kvo) do { \
    _Pragma("unroll") \
    for (int i_ = 0; i_ < 4; ++i_){ \
      const int n_ = i_*256 + tid, kr_ = n_ >> 4, c_ = n_ & 15; \
      const u16* gp_ = kb + (size_t)((kvo) + kr_) * QKV_LD + ((c_ ^ (kr_ & 7)) << 3); \
      __builtin_amdgcn_global_load_lds((AS1 void*)gp_, (AS3 void*)&Ks[buf][n_*8], 16, 0, 0); \
    } \
    const u16* vsrc_ = vtb + ((kvo) >> 6) * 8192; \
    _Pragma("unroll") \
    for (int i_ = 0; i_ < 4; ++i_){ \
      const int n_ = i_*256 + tid; \
      __builtin_amdgcn_global_load_lds((AS1 void*)(vsrc_ + n_*8), \
                                       (AS3 void*)&Vs[buf][n_*8], 16, 0, 0); \
    } \
  } while(0)

  STAGE(0, 0);
  __syncthreads();
  int cur = 0;

  for (int t = 0; t < NT/64; ++t){
    const int kv0 = t * 64;
    if (t + 1 < NT/64) STAGE(cur ^ 1, kv0 + 64);

    // mask for this tile: lane's k-locals are b32*32 + r8*8 + 4*hi + j
    fv4 mA[4], mB[4];
    #pragma unroll
    for (int r8 = 0; r8 < 4; ++r8){
      mA[r8] = *reinterpret_cast<const fv4*>(&mkp[kv0      + r8*8 + hi*4]);
      mB[r8] = *reinterpret_cast<const fv4*>(&mkp[kv0 + 32 + r8*8 + hi*4]);
    }

    // S^T = K Q^T: d0 keys kv0+0..31, d1 keys kv0+32..63; lane owns q-col l31
    f32x16 d0 = {}, d1 = {};
    __builtin_amdgcn_s_setprio(1);
    #pragma unroll
    for (int s = 0; s < 8; ++s){
      const int cg = s*2 + hi;
      s16x8 kf0 = *reinterpret_cast<const s16x8*>(
          &Ks[cur][ l31*128      + ((cg ^ (l31 & 7)) << 3) ]);
      s16x8 kf1 = *reinterpret_cast<const s16x8*>(
          &Ks[cur][ (32+l31)*128 + ((cg ^ (l31 & 7)) << 3) ]);
      d0 = ATT_MFMA(kf0, qf[s], d0);
      d1 = ATT_MFMA(kf1, qf[s], d1);
    }
    __builtin_amdgcn_s_setprio(0);

    // row max over raw scores: max3-friendly tree, then cross-half
    float mx0 = fmaxf(d0[0], d0[1]), mx1 = fmaxf(d0[2], d0[3]);
    float mx2 = fmaxf(d1[0], d1[1]), mx3 = fmaxf(d1[2], d1[3]);
    #pragma unroll
    for (int r = 4; r < 16; r += 4){
      mx0 = fmaxf(mx0, fmaxf(d0[r],   d0[r+1]));
      mx1 = fmaxf(mx1, fmaxf(d0[r+2], d0[r+3]));
      mx2 = fmaxf(mx2, fmaxf(d1[r],   d1[r+1]));
      mx3 = fmaxf(mx3, fmaxf(d1[r+2], d1[r+3]));
    }
    float tmx = fmaxf(fmaxf(mx0, mx1), fmaxf(mx2, mx3));
    tmx = fmaxf(tmx, __shfl_xor(tmx, 32));

    // T13 defer-max (raw-score threshold 64 ~ 8 nats)
    if (!__all(tmx <= mrun + 64.f)){
      const float mn = fmaxf(mrun, tmx);
      const float corr = __builtin_amdgcn_exp2f((mrun - mn) * C1F);
      mrun = mn; lrun *= corr;
      #pragma unroll
      for (int r = 0; r < 16; ++r){
        const int qs = (r & 3) + 8*(r >> 2) + 4*hi;
        const float cq = __shfl(corr, qs);
        o0[r] *= cq; o1[r] *= cq; o2[r] *= cq; o3[r] *= cq;
      }
    }

    // p = exp2(fma(s, c1, -m*c1)) * mask; in-place into d0/d1; accumulate l
    const float mm = mrun * C1F;
    float ts = 0.f;
    #pragma unroll
    for (int r = 0; r < 16; ++r){
      const int r8 = r >> 2, j = r & 3;
      const float p0 = __builtin_amdgcn_exp2f(fmaf(d0[r], C1F, -mm)) * mA[r8][j];
      const float p1 = __builtin_amdgcn_exp2f(fmaf(d1[r], C1F, -mm)) * mB[r8][j];
      d0[r] = p0; d1[r] = p1; ts += p0 + p1;
    }
    ts += __shfl_xor(ts, 32);
    lrun += ts;

    // pack p -> bf16 pairs
    unsigned pku[2][4][2];
    #pragma unroll
    for (int r8 = 0; r8 < 4; ++r8){
      pku[0][r8][0] = pack2bf(d0[4*r8+0], d0[4*r8+1]);
      pku[0][r8][1] = pack2bf(d0[4*r8+2], d0[4*r8+3]);
      pku[1][r8][0] = pack2bf(d1[4*r8+0], d1[4*r8+1]);
      pku[1][r8][1] = pack2bf(d1[4*r8+2], d1[4*r8+3]);
    }

    // PV: per k-step build A-frag with 2 permlane32_swap, then 4 dk-blocks.
    // vf offset (u16): cg*1024 + dk*8, dk = dkb*32 + l31, cg = ks*2 + hi.
    const int vb0 = hi*1024 + l31*8;
    #pragma unroll
    for (int ks = 0; ks < 4; ++ks){
      const int bb = ks >> 1, rlo = (ks & 1) * 2;
      int u0 = (int)pku[bb][rlo][0],   u1 = (int)pku[bb][rlo][1];
      int v0 = (int)pku[bb][rlo+1][0], v1 = (int)pku[bb][rlo+1][1];
      asm("v_permlane32_swap_b32 %0, %1" : "+v"(u0), "+v"(v0));
      asm("v_permlane32_swap_b32 %0, %1" : "+v"(u1), "+v"(v1));
      union { i32x4 i; s16x8 hv; } pu;
      pu.i[0] = u0; pu.i[1] = u1; pu.i[2] = v0; pu.i[3] = v1;
      const int off = ks*2048 + vb0;
      s16x8 vf0 = *reinterpret_cast<const s16x8*>(&Vs[cur][ off       ]);
      s16x8 vf1 = *reinterpret_cast<const s16x8*>(&Vs[cur][ off + 256 ]);
      s16x8 vf2 = *reinterpret_cast<const s16x8*>(&Vs[cur][ off + 512 ]);
      s16x8 vf3 = *reinterpret_cast<const s16x8*>(&Vs[cur][ off + 768 ]);
      __builtin_amdgcn_s_setprio(1);
      o0 = ATT_MFMA(pu.hv, vf0, o0);
      o1 = ATT_MFMA(pu.hv, vf1, o1);
      o2 = ATT_MFMA(pu.hv, vf2, o2);
      o3 = ATT_MFMA(pu.hv, vf3, o3);
      __builtin_amdgcn_s_setprio(0);
    }

    __syncthreads();
    cur ^= 1;
  }

  // epilogue: O[q][dk] regs: col dk = dkblk*32 + l31, row q = (r&3)+8*(r>>2)+4*hi
  #pragma unroll
  for (int r = 0; r < 16; ++r){
    const int qs = (r & 3) + 8*(r >> 2) + 4*hi;
    const float lr = __shfl(lrun, qs);
    const float rl = (lr > 0.f) ? (1.f / lr) : 0.f;
    const int row = q0 + w*32 + qs;
    u16* cp = ctxb + (size_t)(b*NT + row) * ND + h*NDK + l31;
    cp[0]  = f2bf(o0[r] * rl);
    cp[32] = f2bf(o1[r] * rl);
    cp[64] = f2bf(o2[r] * rl);
    cp[96] = f2bf(o3[r] * rl);
  }
#undef STAGE
}

// ---------------------------------------------------------------- launcher
extern "C" void kernel_launch(void* const* d_in, const int* in_sizes, int n_in,
                              void* d_out, int out_size, void* d_ws, size_t ws_size,
                              hipStream_t stream) {
  const float* x      = (const float*)d_in[0];
  const float* mask   = (const float*)d_in[1];
  const float* Wqkv   = (const float*)d_in[2];
  const float* bqkv   = (const float*)d_in[3];
  const float* Wout   = (const float*)d_in[4];
  const float* bout   = (const float*)d_in[5];
  const float* fsmn_w = (const float*)d_in[6];
  float* out = (float*)d_out;

  // workspace layout (bytes); vT is written BY gemm<0> (which reads xb) -> no aliasing.
  char* ws = (char*)d_ws;
  u16* xb    = (u16*)ws;                         // 16,777,216
  u16* wqkvT = (u16*)(ws + 16777216);            //  1,572,864
  u16* woutT = (u16*)(ws + 18350080);            //    524,288
  u16* qkvb  = (u16*)(ws + 18874368);            // 50,331,648
  u16* ctxb  = (u16*)(ws + 69206016);            // 16,777,216
  u16* vT    = (u16*)(ws + 85983232);            // 16,777,216  (total ~103 MB)

  prep_kernel<<<2048, 256, 0, stream>>>(x, xb, Wqkv, wqkvT, Wout, woutT);
  gemm_bt<0><<<dim3(1536/128, 16384/128), 256, 0, stream>>>(
      xb, wqkvT, bqkv, qkvb, nullptr, vT, nullptr, nullptr, nullptr, NB*NT, QKV_LD, ND);
  attn_kernel<<<dim3(8, 64), 256, 0, stream>>>(qkvb, vT, mask, ctxb);
  gemm_bt<1><<<dim3(512/128, 16384/128), 256, 0, stream>>>(
      ctxb, woutT, bout, nullptr, out, nullptr, qkvb, mask, fsmn_w, NB*NT, ND, ND);
}

// Round 16
// 129.194 us; speedup vs baseline: 1.3370x; 1.2524x over previous
//
#include <hip/hip_runtime.h>
#include <hip/hip_bf16.h>
#include <stdint.h>

// Problem constants (from reference)
#define NB 8
#define NT 2048
#define ND 512
#define NH 4
#define NDK 128
#define QKV_LD 1536   // row stride of qkv buffer (3*D)
#define KW 11

typedef unsigned short u16;
typedef __attribute__((ext_vector_type(4))) float f32x4;
typedef __attribute__((ext_vector_type(16))) float f32x16;
typedef __attribute__((ext_vector_type(4))) float fv4;
typedef __attribute__((ext_vector_type(8))) short s16x8;   // 8 bf16 = 4 VGPR
typedef __attribute__((ext_vector_type(4))) unsigned short u16x4;
typedef __attribute__((ext_vector_type(4))) int i32x4;

#define AS1 __attribute__((address_space(1)))
#define AS3 __attribute__((address_space(3)))

__device__ __forceinline__ u16 f2bf(float f){
  unsigned u = __float_as_uint(f);
  u += 0x7fffu + ((u >> 16) & 1u);      // RNE
  return (u16)(u >> 16);
}
__device__ __forceinline__ float bf2f(u16 h){ return __uint_as_float(((unsigned)h) << 16); }
__device__ __forceinline__ unsigned pack2bf(float a, float b){
  float2 t; t.x = a; t.y = b;
  __hip_bfloat162 h = __float22bfloat162_rn(t);
  return *reinterpret_cast<unsigned*>(&h);
}

// ---------------------------------------------------------------- fused prep:
// blocks [0,1024): x -> bf16 (grid-stride)
// blocks [1024,1792): Wqkv transpose+cvt; [1792,2048): Wout transpose+cvt
// blocks [2048,2056): per-batch mask scan -> compact key index list + count
__device__ __forceinline__ void transpose_body(
    const float* __restrict__ in, u16* __restrict__ out, int R, int C,
    int bx, int by, int tid)
{
  __shared__ float tile[32][33];
  const int cb = bx * 32, rb = by * 32;
  const int tx = tid & 31, ty = tid >> 5;   // (32,8)
  #pragma unroll
  for (int i = 0; i < 4; ++i)
    tile[ty + i*8][tx] = in[(size_t)(rb + ty + i*8) * C + cb + tx];
  __syncthreads();
  #pragma unroll
  for (int i = 0; i < 4; ++i)
    out[(size_t)(cb + ty + i*8) * R + rb + tx] = f2bf(tile[tx][ty + i*8]);
}

__global__ void prep_kernel(const float* __restrict__ x, u16* __restrict__ xb,
                            const float* __restrict__ Wqkv, u16* __restrict__ wqkvT,
                            const float* __restrict__ Wout, u16* __restrict__ woutT,
                            const float* __restrict__ mask, u16* __restrict__ idxb,
                            int* __restrict__ cntb)
{
  const int bid = blockIdx.x, tid = threadIdx.x;
  if (bid < 1024){
    const int n4 = (NB*NT*ND)/4;
    for (int i = bid*256 + tid; i < n4; i += 1024*256){
      float4 v = reinterpret_cast<const float4*>(x)[i];
      u16x4 o = { f2bf(v.x), f2bf(v.y), f2bf(v.z), f2bf(v.w) };
      reinterpret_cast<u16x4*>(xb)[i] = o;
    }
  } else if (bid < 1792){
    const int idx = bid - 1024;              // grid (48,16)
    transpose_body(Wqkv, wqkvT, 512, 1536, idx % 48, idx / 48, tid);
  } else if (bid < 2048){
    const int idx = bid - 1792;              // grid (16,16)
    transpose_body(Wout, woutT, 512, 512, idx % 16, idx / 16, tid);
  } else {
    // per-batch mask scan: idx list of valid keys (ascending), count, 64-pad with 0
    const int b = bid - 2048;
    __shared__ int s[256];
    const float* mb = mask + (size_t)b * NT;
    float4 a = *reinterpret_cast<const float4*>(&mb[tid*8]);
    float4 c4 = *reinterpret_cast<const float4*>(&mb[tid*8 + 4]);
    float vals[8] = {a.x, a.y, a.z, a.w, c4.x, c4.y, c4.z, c4.w};
    int lc = 0;
    #pragma unroll
    for (int j = 0; j < 8; ++j) lc += (vals[j] != 0.f);
    s[tid] = lc; __syncthreads();
    #pragma unroll
    for (int d = 1; d < 256; d <<= 1){
      const int v = (tid >= d) ? s[tid - d] : 0;
      __syncthreads();
      s[tid] += v;
      __syncthreads();
    }
    const int excl = s[tid] - lc;
    const int total = s[255];
    u16* ib = idxb + (size_t)b * NT;
    int off = excl;
    #pragma unroll
    for (int j = 0; j < 8; ++j)
      if (vals[j] != 0.f) ib[off++] = (u16)(tid*8 + j);
    const int padded = (total + 63) & ~63;
    for (int j = total + tid; j < padded; j += 256) ib[j] = 0;
    if (tid == 0) cntb[b] = total;
  }
}

// ---------------------------------------------------------------- KV compaction
// Per (batch, 64-key compact tile): gather K rows -> kcb[bh][j][128] (plain rows) and
// V -> vtc[bh][tile][kg][dk][8] (subtiled 16B chunks, R15 layout) via LDS transpose.
__global__ __launch_bounds__(256) void kv_compact(
    const u16* __restrict__ qkvb, const u16* __restrict__ idxb,
    const int* __restrict__ cntb, u16* __restrict__ kcb, u16* __restrict__ vtc)
{
  const int b = blockIdx.y, tile = blockIdx.x, tid = threadIdx.x;
  const int total = cntb[b];
  if (tile * 64 >= ((total + 63) & ~63)) return;
  __shared__ u16 idx64[64];
  __shared__ u16 vbuf[64 * 128];
  if (tid < 64) idx64[tid] = idxb[(size_t)b * NT + tile*64 + tid];
  __syncthreads();
  #pragma unroll
  for (int h = 0; h < 4; ++h){
    // K: 1024 x 16B chunks, contiguous row copies
    #pragma unroll
    for (int i = 0; i < 4; ++i){
      const int c = i*256 + tid, key = c >> 4, ck = c & 15;
      const int srcT = idx64[key];
      const u16* sp = qkvb + ((size_t)b*NT + srcT)*QKV_LD + ND + h*NDK + ck*8;
      u16* dp = kcb + ((size_t)(b*4+h)*NT + tile*64 + key)*NDK + ck*8;
      *reinterpret_cast<s16x8*>(dp) = *reinterpret_cast<const s16x8*>(sp);
    }
    // V: stage rows -> LDS, then write subtiled [kg][dk][8keys]
    #pragma unroll
    for (int i = 0; i < 4; ++i){
      const int c = i*256 + tid, key = c >> 4, ck = c & 15;
      const int srcT = idx64[key];
      const u16* sp = qkvb + ((size_t)b*NT + srcT)*QKV_LD + 2*ND + h*NDK + ck*8;
      *reinterpret_cast<s16x8*>(&vbuf[key*128 + ck*8]) =
          *reinterpret_cast<const s16x8*>(sp);
    }
    __syncthreads();
    u16* vt = vtc + ((size_t)(b*4+h)*32 + tile) * 8192;
    #pragma unroll
    for (int i = 0; i < 4; ++i){
      const int c = i*256 + tid, kg = c >> 7, dk = c & 127;
      s16x8 ov;
      #pragma unroll
      for (int e = 0; e < 8; ++e) ov[e] = (short)vbuf[(kg*8 + e)*128 + dk];
      *reinterpret_cast<s16x8*>(&vt[c*8]) = ov;
    }
    __syncthreads();
  }
}

// ---------------------------------------------------------------- bf16 GEMM  C = A * Bt^T + bias
// BK=64 + XOR swizzle (rule #21, verified R13).
// EPI==0: C -> bf16.  EPI==1: C -> f32 out with FUSED FSMN epilogue.
template<int EPI>
__global__ __launch_bounds__(256, 2) void gemm_bt(
    const u16* __restrict__ A, const u16* __restrict__ Bt, const float* __restrict__ bias,
    u16* __restrict__ Cb, float* __restrict__ Cf,
    const u16* __restrict__ qkvb, const float* __restrict__ mask,
    const float* __restrict__ fsmn_w,
    int M, int N, int Kd)
{
  __shared__ u16 As[128 * 64];
  __shared__ u16 Bs[128 * 64];
  const int tid = threadIdx.x;
  const int m0 = blockIdx.y * 128, n0 = blockIdx.x * 128;
  const int w = tid >> 6, l = tid & 63, wr = w >> 1, wc = w & 1;
  const int r15 = l & 15, g = l >> 4;

  f32x4 acc[4][4] = {};

  const int r0 = tid >> 3;
  const int scol8 = ((tid & 7) ^ (r0 & 7)) << 3;   // u16 offset within the 64-col row
  const u16* Ag = A  + (size_t)(m0 + r0) * Kd + scol8;
  const u16* Bg = Bt + (size_t)(n0 + r0) * Kd + scol8;
  u16* Al = &As[(size_t)tid * 8];
  u16* Bl = &Bs[(size_t)tid * 8];

  for (int k0 = 0; k0 < Kd; k0 += 64){
    #pragma unroll
    for (int i = 0; i < 4; ++i)
      __builtin_amdgcn_global_load_lds((AS1 void*)(Ag + (size_t)(i*32) * Kd + k0),
                                       (AS3 void*)(Al + i*2048), 16, 0, 0);
    #pragma unroll
    for (int i = 0; i < 4; ++i)
      __builtin_amdgcn_global_load_lds((AS1 void*)(Bg + (size_t)(i*32) * Kd + k0),
                                       (AS3 void*)(Bl + i*2048), 16, 0, 0);
    __syncthreads();
    #pragma unroll
    for (int kk = 0; kk < 2; ++kk){
      s16x8 af[4], bfr[4];
      #pragma unroll
      for (int m = 0; m < 4; ++m){
        const int R = wr*64 + m*16 + r15;
        af[m] = *reinterpret_cast<const s16x8*>(
            &As[R*64 + (((kk*4 + g) ^ (r15 & 7)) << 3)]);
      }
      #pragma unroll
      for (int n = 0; n < 4; ++n){
        const int R = wc*64 + n*16 + r15;
        bfr[n] = *reinterpret_cast<const s16x8*>(
            &Bs[R*64 + (((kk*4 + g) ^ (r15 & 7)) << 3)]);
      }
      #pragma unroll
      for (int m = 0; m < 4; ++m){
        #pragma unroll
        for (int n = 0; n < 4; ++n)
          acc[m][n] = __builtin_amdgcn_mfma_f32_16x16x32_bf16(af[m], bfr[n], acc[m][n], 0, 0, 0);
      }
    }
    __syncthreads();
  }

  if (EPI == 0){
    #pragma unroll
    for (int m = 0; m < 4; ++m){
      const int gr0 = m0 + wr*64 + m*16 + g*4;
      #pragma unroll
      for (int n = 0; n < 4; ++n){
        const int gc = n0 + wc*64 + n*16 + r15;
        const float bv = bias[gc];
        #pragma unroll
        for (int j = 0; j < 4; ++j)
          Cb[(size_t)(gr0 + j) * N + gc] = f2bf(acc[m][n][j] + bv);
      }
    }
  } else {
    // fused FSMN epilogue
    float wv[4][KW];
    #pragma unroll
    for (int n = 0; n < 4; ++n){
      const int gc = n0 + wc*64 + n*16 + r15;
      #pragma unroll
      for (int i = 0; i < KW; ++i) wv[n][i] = fsmn_w[gc*KW + i];
    }
    #pragma unroll
    for (int m = 0; m < 4; ++m){
      const int gr0 = m0 + wr*64 + m*16 + g*4;
      const int bb = gr0 >> 11, t0 = gr0 & 2047;
      const float* mb = mask + (size_t)bb * NT;
      float mk[14];
      #pragma unroll
      for (int i = 0; i < 14; ++i){
        const int tau = t0 - 5 + i;
        mk[i] = ((unsigned)tau < (unsigned)NT) ? mb[tau] : 0.f;
      }
      #pragma unroll
      for (int n = 0; n < 4; ++n){
        const int gc = n0 + wc*64 + n*16 + r15;
        const float bv = bias[gc];
        const u16* vb = qkvb + (size_t)bb * NT * QKV_LD + 2*ND + gc;
        float vmv[14];
        #pragma unroll
        for (int i = 0; i < 14; ++i){
          const ptrdiff_t tau = t0 - 5 + i;
          vmv[i] = mk[i] * bf2f(vb[tau * QKV_LD]);   // mk=0 zeroes OOB taps
        }
        #pragma unroll
        for (int j = 0; j < 4; ++j){
          float conv = vmv[5 + j];                    // vm[t] residual term
          #pragma unroll
          for (int i = 0; i < KW; ++i) conv = fmaf(wv[n][i], vmv[j + i], conv);
          Cf[(size_t)(gr0 + j) * N + gc] = acc[m][n][j] + bv + mk[5 + j] * conv;
        }
      }
    }
  }
}

// ---------------------------------------------------------------- flash attention, COMPACTED KEYS
// R13/R15 structure, but K/V come from per-batch compacted buffers (only unmasked keys,
// ~50% of 2048). ntiles = ceil(cnt/64) runtime; last tile applies kidx<cnt predicate;
// all other tiles need NO mask at all. K rows 256B compact (better coalescing), V in
// subtiled layout (linear stage, conflict-free PV reads).
// DO NOT raise launch_bounds 2nd arg (R9: (256,3) -> 84 VGPR + scratch spill, 2.2x slower).
#define ATT_MFMA(a, bb, c) __builtin_amdgcn_mfma_f32_32x32x16_bf16(a, bb, c, 0, 0, 0)
#define C1F 0.12751741567f   /* (1/sqrt(128)) * log2(e) */

__global__ __launch_bounds__(256, 2) void attn_kernel(
    const u16* __restrict__ qkvb, const u16* __restrict__ kcb,
    const u16* __restrict__ vtc, const int* __restrict__ cntb,
    u16* __restrict__ ctxb)
{
  __shared__ u16 Ks[2][64 * 128];   // [key][dk], swizzled 16B chunks
  __shared__ u16 Vs[2][8 * 128 * 8];// [kg][dk][8 keys] subtiled (linear image of vtc tile)
  const int tid = threadIdx.x;
  const int w = tid >> 6, l = tid & 63, l31 = l & 31, hi = l >> 5;

  // XCD-bijective remap: all 16 q-blocks of one bh land on one XCD (K/V L2 locality)
  const int lin = blockIdx.x + blockIdx.y * 8;    // grid = (8, 64)
  const int xcd = lin & 7, jj = lin >> 3;         // jj 0..63
  const int bh = xcd * 4 + (jj & 3), qblk = jj >> 2;
  const int b = bh >> 2, h = bh & 3;
  const int q0 = qblk * 128;

  const u16* qptr = qkvb + (size_t)b * NT * QKV_LD + h * NDK;
  const u16* kb   = kcb + (size_t)bh * NT * NDK;
  const u16* vtb  = vtc + (size_t)bh * 32 * 8192;
  const int total = cntb[b];
  const int ntiles = (total + 63) >> 6;

  // Q in registers (B-operand): lane holds Q[q0+w*32+l31][s*16 + hi*8 .. +7]
  s16x8 qf[8];
  {
    const u16* qrow = qptr + (size_t)(q0 + w*32 + l31) * QKV_LD;
    #pragma unroll
    for (int s = 0; s < 8; ++s)
      qf[s] = *reinterpret_cast<const s16x8*>(qrow + s*16 + hi*8);
  }

  float mrun = -1e30f, lrun = 0.f;
  f32x16 o0 = {}, o1 = {}, o2 = {}, o3 = {};

  // K chunk c: key = c>>4, slot = c&15 (256B compact rows, source XOR-swizzled).
  // V: contiguous linear copy of the 16KB subtiled vtc tile.
#define STAGE(buf, kvo) do { \
    _Pragma("unroll") \
    for (int i_ = 0; i_ < 4; ++i_){ \
      const int n_ = i_*256 + tid, kr_ = n_ >> 4, c_ = n_ & 15; \
      const u16* gp_ = kb + (size_t)((kvo) + kr_) * NDK + ((c_ ^ (kr_ & 7)) << 3); \
      __builtin_amdgcn_global_load_lds((AS1 void*)gp_, (AS3 void*)&Ks[buf][n_*8], 16, 0, 0); \
    } \
    const u16* vsrc_ = vtb + ((kvo) >> 6) * 8192; \
    _Pragma("unroll") \
    for (int i_ = 0; i_ < 4; ++i_){ \
      const int n_ = i_*256 + tid; \
      __builtin_amdgcn_global_load_lds((AS1 void*)(vsrc_ + n_*8), \
                                       (AS3 void*)&Vs[buf][n_*8], 16, 0, 0); \
    } \
  } while(0)

  if (ntiles > 0) STAGE(0, 0);
  __syncthreads();
  int cur = 0;

  for (int t = 0; t < ntiles; ++t){
    const int kv0 = t * 64;
    if (t + 1 < ntiles) STAGE(cur ^ 1, kv0 + 64);

    // S^T = K Q^T: d0 keys kv0+0..31, d1 keys kv0+32..63; lane owns q-col l31
    f32x16 d0 = {}, d1 = {};
    __builtin_amdgcn_s_setprio(1);
    #pragma unroll
    for (int s = 0; s < 8; ++s){
      const int cg = s*2 + hi;
      s16x8 kf0 = *reinterpret_cast<const s16x8*>(
          &Ks[cur][ l31*128      + ((cg ^ (l31 & 7)) << 3) ]);
      s16x8 kf1 = *reinterpret_cast<const s16x8*>(
          &Ks[cur][ (32+l31)*128 + ((cg ^ (l31 & 7)) << 3) ]);
      d0 = ATT_MFMA(kf0, qf[s], d0);
      d1 = ATT_MFMA(kf1, qf[s], d1);
    }
    __builtin_amdgcn_s_setprio(0);

    // row max over raw scores: max3-friendly tree, then cross-half
    float mx0 = fmaxf(d0[0], d0[1]), mx1 = fmaxf(d0[2], d0[3]);
    float mx2 = fmaxf(d1[0], d1[1]), mx3 = fmaxf(d1[2], d1[3]);
    #pragma unroll
    for (int r = 4; r < 16; r += 4){
      mx0 = fmaxf(mx0, fmaxf(d0[r],   d0[r+1]));
      mx1 = fmaxf(mx1, fmaxf(d0[r+2], d0[r+3]));
      mx2 = fmaxf(mx2, fmaxf(d1[r],   d1[r+1]));
      mx3 = fmaxf(mx3, fmaxf(d1[r+2], d1[r+3]));
    }
    float tmx = fmaxf(fmaxf(mx0, mx1), fmaxf(mx2, mx3));
    tmx = fmaxf(tmx, __shfl_xor(tmx, 32));

    // T13 defer-max (raw-score threshold 64 ~ 8 nats)
    if (!__all(tmx <= mrun + 64.f)){
      const float mn = fmaxf(mrun, tmx);
      const float corr = __builtin_amdgcn_exp2f((mrun - mn) * C1F);
      mrun = mn; lrun *= corr;
      #pragma unroll
      for (int r = 0; r < 16; ++r){
        const int qs = (r & 3) + 8*(r >> 2) + 4*hi;
        const float cq = __shfl(corr, qs);
        o0[r] *= cq; o1[r] *= cq; o2[r] *= cq; o3[r] *= cq;
      }
    }

    // p = exp2(fma(s, c1, -m*c1)); NO mask (keys pre-compacted); last tile: kidx<cnt
    const float mm = mrun * C1F;
    float ts = 0.f;
    if (t + 1 < ntiles){
      #pragma unroll
      for (int r = 0; r < 16; ++r){
        const float p0 = __builtin_amdgcn_exp2f(fmaf(d0[r], C1F, -mm));
        const float p1 = __builtin_amdgcn_exp2f(fmaf(d1[r], C1F, -mm));
        d0[r] = p0; d1[r] = p1; ts += p0 + p1;
      }
    } else {
      #pragma unroll
      for (int r = 0; r < 16; ++r){
        const int kidx = kv0 + (r >> 2)*8 + 4*hi + (r & 3);
        const float p0 = (kidx      < total) ? __builtin_amdgcn_exp2f(fmaf(d0[r], C1F, -mm)) : 0.f;
        const float p1 = (kidx + 32 < total) ? __builtin_amdgcn_exp2f(fmaf(d1[r], C1F, -mm)) : 0.f;
        d0[r] = p0; d1[r] = p1; ts += p0 + p1;
      }
    }
    ts += __shfl_xor(ts, 32);
    lrun += ts;

    // pack p -> bf16 pairs
    unsigned pku[2][4][2];
    #pragma unroll
    for (int r8 = 0; r8 < 4; ++r8){
      pku[0][r8][0] = pack2bf(d0[4*r8+0], d0[4*r8+1]);
      pku[0][r8][1] = pack2bf(d0[4*r8+2], d0[4*r8+3]);
      pku[1][r8][0] = pack2bf(d1[4*r8+0], d1[4*r8+1]);
      pku[1][r8][1] = pack2bf(d1[4*r8+2], d1[4*r8+3]);
    }

    // PV: per k-step build A-frag with 2 permlane32_swap, then 4 dk-blocks.
    // vf offset (u16): kg*1024 + dk*8, dk = dkb*32 + l31, kg = ks*2 + hi.
    const int vb0 = hi*1024 + l31*8;
    #pragma unroll
    for (int ks = 0; ks < 4; ++ks){
      const int bb = ks >> 1, rlo = (ks & 1) * 2;
      int u0 = (int)pku[bb][rlo][0],   u1 = (int)pku[bb][rlo][1];
      int v0 = (int)pku[bb][rlo+1][0], v1 = (int)pku[bb][rlo+1][1];
      asm("v_permlane32_swap_b32 %0, %1" : "+v"(u0), "+v"(v0));
      asm("v_permlane32_swap_b32 %0, %1" : "+v"(u1), "+v"(v1));
      union { i32x4 i; s16x8 hv; } pu;
      pu.i[0] = u0; pu.i[1] = u1; pu.i[2] = v0; pu.i[3] = v1;
      const int off = ks*2048 + vb0;
      s16x8 vf0 = *reinterpret_cast<const s16x8*>(&Vs[cur][ off       ]);
      s16x8 vf1 = *reinterpret_cast<const s16x8*>(&Vs[cur][ off + 256 ]);
      s16x8 vf2 = *reinterpret_cast<const s16x8*>(&Vs[cur][ off + 512 ]);
      s16x8 vf3 = *reinterpret_cast<const s16x8*>(&Vs[cur][ off + 768 ]);
      __builtin_amdgcn_s_setprio(1);
      o0 = ATT_MFMA(pu.hv, vf0, o0);
      o1 = ATT_MFMA(pu.hv, vf1, o1);
      o2 = ATT_MFMA(pu.hv, vf2, o2);
      o3 = ATT_MFMA(pu.hv, vf3, o3);
      __builtin_amdgcn_s_setprio(0);
    }

    __syncthreads();
    cur ^= 1;
  }

  // epilogue: O[q][dk] regs: col dk = dkblk*32 + l31, row q = (r&3)+8*(r>>2)+4*hi
  #pragma unroll
  for (int r = 0; r < 16; ++r){
    const int qs = (r & 3) + 8*(r >> 2) + 4*hi;
    const float lr = __shfl(lrun, qs);
    const float rl = (lr > 0.f) ? (1.f / lr) : 0.f;
    const int row = q0 + w*32 + qs;
    u16* cp = ctxb + (size_t)(b*NT + row) * ND + h*NDK + l31;
    cp[0]  = f2bf(o0[r] * rl);
    cp[32] = f2bf(o1[r] * rl);
    cp[64] = f2bf(o2[r] * rl);
    cp[96] = f2bf(o3[r] * rl);
  }
#undef STAGE
}

// ---------------------------------------------------------------- launcher
extern "C" void kernel_launch(void* const* d_in, const int* in_sizes, int n_in,
                              void* d_out, int out_size, void* d_ws, size_t ws_size,
                              hipStream_t stream) {
  const float* x      = (const float*)d_in[0];
  const float* mask   = (const float*)d_in[1];
  const float* Wqkv   = (const float*)d_in[2];
  const float* bqkv   = (const float*)d_in[3];
  const float* Wout   = (const float*)d_in[4];
  const float* bout   = (const float*)d_in[5];
  const float* fsmn_w = (const float*)d_in[6];
  float* out = (float*)d_out;

  // workspace layout (bytes): xb dead after gemm<0> -> kcb reuses its region.
  char* ws = (char*)d_ws;
  u16* xb    = (u16*)ws;                         // 16,777,216  (kcb after gemm0)
  u16* kcb   = (u16*)ws;
  u16* wqkvT = (u16*)(ws + 16777216);            //  1,572,864
  u16* woutT = (u16*)(ws + 18350080);            //    524,288
  u16* qkvb  = (u16*)(ws + 18874368);            // 50,331,648
  u16* ctxb  = (u16*)(ws + 69206016);            // 16,777,216
  u16* vtc   = (u16*)(ws + 85983232);            // 16,777,216
  u16* idxb  = (u16*)(ws + 102760448);           //     32,768
  int* cntb  = (int*)(ws + 102793216);           //         32  -> total 102,793,248

  prep_kernel<<<2056, 256, 0, stream>>>(x, xb, Wqkv, wqkvT, Wout, woutT,
                                        mask, idxb, cntb);
  gemm_bt<0><<<dim3(1536/128, 16384/128), 256, 0, stream>>>(
      xb, wqkvT, bqkv, qkvb, nullptr, nullptr, nullptr, nullptr, NB*NT, QKV_LD, ND);
  kv_compact<<<dim3(32, 8), 256, 0, stream>>>(qkvb, idxb, cntb, kcb, vtc);
  attn_kernel<<<dim3(8, 64), 256, 0, stream>>>(qkvb, kcb, vtc, cntb, ctxb);
  gemm_bt<1><<<dim3(512/128, 16384/128), 256, 0, stream>>>(
      ctxb, woutT, bout, nullptr, out, qkvb, mask, fsmn_w, NB*NT, ND, ND);
}